// Round 2
// baseline (100.992 us; speedup 1.0000x reference)
//
#include <hip/hip_runtime.h>
#include <stdint.h>

static constexpr int P       = 24;
static constexpr int EMB_D   = 32;
static constexpr int N_AC    = 38;
static constexpr int N_AT    = 6;
static constexpr int N_RC    = 21;
static constexpr int MAXSEQ  = 1024;
static constexpr int VEC_OUT = 64;
static constexpr int SC_OUT  = 256;
static constexpr int FEAT    = 3 * VEC_OUT + SC_OUT;   // 448
static constexpr int CT      = N_AC * N_AT;            // 228 fused code*type combos
static constexpr int NROWS   = P * CT;                 // 5472
static constexpr int ROWB    = SC_OUT * 2;             // 512 B per bf16 row
static constexpr uint32_t ZROWB = (uint32_t)NROWS * ROWB;  // zero row byte offset

__device__ __forceinline__ unsigned short f2bf(float f) {
    uint32_t x = __float_as_uint(f);
    uint32_t r = (x + 0x7FFFu + ((x >> 16) & 1u)) >> 16;  // RNE
    return (unsigned short)r;
}

__global__ void init_bounds(int* __restrict__ starts, int* __restrict__ ends, int R) {
    int i = blockIdx.x * blockDim.x + threadIdx.x;
    if (i < R) { starts[i] = 0; ends[i] = 0; }
}

__global__ void find_bounds(const int* __restrict__ ri, int* __restrict__ starts,
                            int* __restrict__ ends, int N) {
    int i = blockIdx.x * blockDim.x + threadIdx.x;
    if (i >= N) return;
    int r = ri[i];
    if (i == 0 || ri[i - 1] != r) starts[r] = i;
    if (i == N - 1 || ri[i + 1] != r) ends[r] = i + 1;
}

// E[(p*n_emb+e)*256 + o] = scale * sum_d Wemb[e*32+d] * Wsc[(sc_base+p*32+d)*256 + o]  (f32 out)
__global__ __launch_bounds__(SC_OUT) void build_f32(
        const float* __restrict__ Wemb, const float* __restrict__ Wsc,
        float* __restrict__ E, int n_emb, int sc_base, float scale) {
    int b = blockIdx.x;
    int p = b / n_emb;
    int e = b % n_emb;
    int o = threadIdx.x;
    const float* wrow = Wemb + (size_t)e * EMB_D;
    const float* scol = Wsc + (size_t)(sc_base + p * EMB_D) * SC_OUT + o;
    float s = 0.f;
#pragma unroll
    for (int d = 0; d < EMB_D; ++d) s += wrow[d] * scol[(size_t)d * SC_OUT];
    E[(size_t)b * SC_OUT + o] = s * scale;
}

// Etab[(j*228 + c*6 + t)] = bf16(Ecode_f[j,c] + Etype_f[j,t]); row NROWS is all-zero pad row.
__global__ __launch_bounds__(SC_OUT) void fuse_table(
        const float* __restrict__ Ec, const float* __restrict__ Et,
        unsigned short* __restrict__ Etab) {
    int b = blockIdx.x, o = threadIdx.x;
    if (b == NROWS) { Etab[(size_t)b * SC_OUT + o] = 0; return; }
    int j = b / CT, ct = b % CT, c = ct / N_AT, t = ct % N_AT;
    float s = Ec[((size_t)j * N_AC + c) * SC_OUT + o] + Et[((size_t)j * N_AT + t) * SC_OUT + o];
    Etab[(size_t)b * SC_OUT + o] = f2bf(s);
}

// per-atom fused table row byte offset (zero row for pad/overflow atoms); padded tail.
__global__ void atom_prep(const int* __restrict__ ri, const int* __restrict__ ac,
                          const int* __restrict__ at, const int* __restrict__ starts,
                          uint32_t* __restrict__ ciArr, int N, int NP) {
    int i = blockIdx.x * blockDim.x + threadIdx.x;
    if (i >= NP) return;
    uint32_t rb = ZROWB;
    if (i < N) {
        int r = ri[i];
        int pos = i - starts[r];
        if (pos < P) rb = (uint32_t)((pos * CT + ac[i] * N_AT + at[i]) * ROWB);
    }
    ciArr[i] = rb;
}

__global__ void copy_coords(const float* __restrict__ src, float* __restrict__ dst, int n) {
    int i = blockIdx.x * blockDim.x + threadIdx.x;
    if (i < n) dst[i] = src[i];
}

__global__ __launch_bounds__(256) void residue_kernel(
        const float* __restrict__ rel, const int* __restrict__ rcode,
        const int* __restrict__ rseq, const int* __restrict__ starts,
        const int* __restrict__ ends, const uint32_t* __restrict__ ciArr,
        const unsigned char* __restrict__ tab, const float* __restrict__ Erc,
        const float* __restrict__ Erix, const float* __restrict__ Wvec,
        float* __restrict__ out_feat, int R, int N) {
    int wid = (blockIdx.x * blockDim.x + threadIdx.x) >> 6;
    int lane = threadIdx.x & 63;
    if (wid >= R) return;
    const int r = wid;
    const int off = starts[r];
    int cnt = ends[r] - off;
    if (cnt > P) cnt = P;

    float4 ea = *reinterpret_cast<const float4*>(Erc + (size_t)rcode[r] * SC_OUT + lane * 4);
    float4 eb = *reinterpret_cast<const float4*>(Erix + (size_t)rseq[r] * SC_OUT + lane * 4);
    float a0 = ea.x + eb.x, a1 = ea.y + eb.y, a2 = ea.z + eb.z, a3 = ea.w + eb.w;
    float v0 = 0.f, v1 = 0.f, v2 = 0.f;
    const int lb = lane * 8;

    for (int j0 = 0; j0 < cnt; j0 += 8) {
        uint2 g[8];
        float w[8], ax[8], ay[8], az[8];
#pragma unroll
        for (int k = 0; k < 8; ++k) {
            int j = j0 + k;
            uint32_t rb = ciArr[off + j];                  // wave-uniform, padded-safe
            rb = (j < cnt) ? rb : ZROWB;
            g[k] = *reinterpret_cast<const uint2*>(tab + rb + lb);
            float wv = Wvec[j * VEC_OUT + lane];           // j < P always
            w[k] = (j < cnt) ? wv : 0.f;
            int ai = off + j;
            if (ai > N - 1) ai = N - 1;                    // clamp (garbage * w=0)
            const float* rp = rel + (size_t)3 * ai;
            ax[k] = rp[0]; ay[k] = rp[1]; az[k] = rp[2];
        }
#pragma unroll
        for (int k = 0; k < 8; ++k) {
            a0 += __uint_as_float(g[k].x << 16);
            a1 += __uint_as_float(g[k].x & 0xFFFF0000u);
            a2 += __uint_as_float(g[k].y << 16);
            a3 += __uint_as_float(g[k].y & 0xFFFF0000u);
            v0 = fmaf(ax[k], w[k], v0);
            v1 = fmaf(ay[k], w[k], v1);
            v2 = fmaf(az[k], w[k], v2);
        }
    }

    const float vs = 0.20412414523193150818f;  // 1/sqrt(24)
    float* frow = out_feat + (size_t)r * FEAT;
    frow[lane * 3 + 0] = v0 * vs;
    frow[lane * 3 + 1] = v1 * vs;
    frow[lane * 3 + 2] = v2 * vs;
    *reinterpret_cast<float4*>(frow + 3 * VEC_OUT + lane * 4) =
        make_float4(a0, a1, a2, a3);
}

extern "C" void kernel_launch(void* const* d_in, const int* in_sizes, int n_in,
                              void* d_out, int out_size, void* d_ws, size_t ws_size,
                              hipStream_t stream) {
    const float* base  = (const float*)d_in[0];
    const float* rel   = (const float*)d_in[1];
    const int*   rcode = (const int*)d_in[2];
    const int*   rseq  = (const int*)d_in[3];
    const int*   acode = (const int*)d_in[4];
    const int*   atype = (const int*)d_in[5];
    const int*   ri    = (const int*)d_in[6];
    const float* Wac   = (const float*)d_in[7];
    const float* Wat   = (const float*)d_in[8];
    const float* Wrc   = (const float*)d_in[9];
    const float* Wri   = (const float*)d_in[10];
    const float* Wv    = (const float*)d_in[11];
    const float* Wsc   = (const float*)d_in[12];

    const int R = in_sizes[0] / 3;
    const int N = in_sizes[6];
    const int NP = N + 64;

    float* out_coords = (float*)d_out;
    float* out_feat   = out_coords + (size_t)R * 3;

    char* ws = (char*)d_ws;
    size_t ofs = 0;
    auto alloc = [&](size_t bytes) {
        void* p = ws + ofs;
        ofs = (ofs + bytes + 255) & ~255ULL;
        return p;
    };
    int*            starts = (int*)alloc((size_t)R * 4);
    int*            ends   = (int*)alloc((size_t)R * 4);
    float*          Ec_f   = (float*)alloc((size_t)P * N_AC * SC_OUT * 4);
    float*          Et_f   = (float*)alloc((size_t)P * N_AT * SC_OUT * 4);
    float*          Erc_f  = (float*)alloc((size_t)N_RC * SC_OUT * 4);
    float*          Erix_f = (float*)alloc((size_t)MAXSEQ * SC_OUT * 4);
    unsigned short* Etab   = (unsigned short*)alloc((size_t)(NROWS + 1) * SC_OUT * 2);
    uint32_t*       ciArr  = (uint32_t*)alloc((size_t)NP * 4);
    (void)ws_size; (void)n_in; (void)out_size;

    const float sc_scale = 0.025f;  // 1/sqrt(1600)

    init_bounds<<<(R + 255) / 256, 256, 0, stream>>>(starts, ends, R);
    find_bounds<<<(N + 255) / 256, 256, 0, stream>>>(ri, starts, ends, N);
    build_f32<<<P * N_AC, SC_OUT, 0, stream>>>(Wac, Wsc, Ec_f, N_AC, 0, sc_scale);
    build_f32<<<P * N_AT, SC_OUT, 0, stream>>>(Wat, Wsc, Et_f, N_AT, P * EMB_D, sc_scale);
    build_f32<<<N_RC,     SC_OUT, 0, stream>>>(Wrc, Wsc, Erc_f, N_RC, 2 * P * EMB_D, sc_scale);
    build_f32<<<MAXSEQ,   SC_OUT, 0, stream>>>(Wri, Wsc, Erix_f, MAXSEQ, 2 * P * EMB_D + EMB_D, sc_scale);
    fuse_table<<<NROWS + 1, SC_OUT, 0, stream>>>(Ec_f, Et_f, Etab);
    atom_prep<<<(NP + 255) / 256, 256, 0, stream>>>(ri, acode, atype, starts, ciArr, N, NP);

    residue_kernel<<<(R + 3) / 4, 256, 0, stream>>>(
        rel, rcode, rseq, starts, ends, ciArr, (const unsigned char*)Etab,
        Erc_f, Erix_f, Wv, out_feat, R, N);

    copy_coords<<<(R * 3 + 255) / 256, 256, 0, stream>>>(base, out_coords, R * 3);
}

// Round 3
// 66.690 us; speedup vs baseline: 1.5143x; 1.5143x over previous
//
#include <hip/hip_runtime.h>
#include <stdint.h>

static constexpr int P       = 24;
static constexpr int EMB_D   = 32;
static constexpr int N_AC    = 38;
static constexpr int N_AT    = 6;
static constexpr int N_RC    = 21;
static constexpr int MAXSEQ  = 1024;
static constexpr int VEC_OUT = 64;
static constexpr int SC_OUT  = 256;
static constexpr int FEAT    = 3 * VEC_OUT + SC_OUT;   // 448
static constexpr int CT      = N_AC * N_AT;            // 228
static constexpr int NROWS   = P * CT;                 // 5472
static constexpr int ROWB    = SC_OUT * 2;             // 512 B bf16 row
static constexpr uint32_t ZROWB = (uint32_t)NROWS * ROWB;  // zero row offset

__device__ __forceinline__ unsigned short f2bf(float f) {
    uint32_t x = __float_as_uint(f);
    uint32_t r = (x + 0x7FFFu + ((x >> 16) & 1u)) >> 16;  // RNE
    return (unsigned short)r;
}

// ---- K1: init bounds + build all four f32 partial tables -------------------
__global__ __launch_bounds__(256) void k1_init_build(
        const float* __restrict__ Wac, const float* __restrict__ Wat,
        const float* __restrict__ Wrc, const float* __restrict__ Wri,
        const float* __restrict__ Wsc,
        float* __restrict__ Ec, float* __restrict__ Et,
        float* __restrict__ Erc, float* __restrict__ Erix,
        int* __restrict__ starts, int* __restrict__ ends, int R) {
    int b = blockIdx.x;
    const int initB = (R + 255) / 256;
    if (b < initB) {
        int i = b * 256 + threadIdx.x;
        if (i < R) { starts[i] = 0; ends[i] = 0; }
        return;
    }
    b -= initB;
    const float* Wemb; float* E; int n_emb, sc_base, idx;
    if (b < P * N_AC) {
        Wemb = Wac; E = Ec; n_emb = N_AC; sc_base = 0; idx = b;
    } else if (b < P * N_AC + P * N_AT) {
        Wemb = Wat; E = Et; n_emb = N_AT; sc_base = P * EMB_D; idx = b - P * N_AC;
    } else if (b < P * N_AC + P * N_AT + N_RC) {
        Wemb = Wrc; E = Erc; n_emb = N_RC; sc_base = 2 * P * EMB_D;
        idx = b - (P * N_AC + P * N_AT);
    } else {
        Wemb = Wri; E = Erix; n_emb = MAXSEQ; sc_base = 2 * P * EMB_D + EMB_D;
        idx = b - (P * N_AC + P * N_AT + N_RC);
    }
    int p = idx / n_emb, e = idx % n_emb;
    int o = threadIdx.x;
    const float* wrow = Wemb + (size_t)e * EMB_D;
    const float* scol = Wsc + (size_t)(sc_base + p * EMB_D) * SC_OUT + o;
    float s = 0.f;
#pragma unroll
    for (int d = 0; d < EMB_D; ++d) s += wrow[d] * scol[(size_t)d * SC_OUT];
    E[(size_t)idx * SC_OUT + o] = s * 0.025f;  // 1/sqrt(1600)
}

// ---- K2: residue run boundaries (ri sorted) --------------------------------
__global__ void k2_find_bounds(const int* __restrict__ ri, int* __restrict__ starts,
                               int* __restrict__ ends, int N) {
    int i = blockIdx.x * blockDim.x + threadIdx.x;
    if (i >= N) return;
    int r = ri[i];
    if (i == 0 || ri[i - 1] != r) starts[r] = i;
    if (i == N - 1 || ri[i + 1] != r) ends[r] = i + 1;
}

// ---- K3: fuse code+type table to bf16  +  build padded per-residue plan ----
__global__ __launch_bounds__(256) void k3_fuse_plan(
        const float* __restrict__ Ec, const float* __restrict__ Et,
        unsigned short* __restrict__ Etab,
        const int* __restrict__ ac, const int* __restrict__ at,
        const int* __restrict__ starts, const int* __restrict__ ends,
        const float* __restrict__ rel, uint4* __restrict__ plan, int R) {
    int b = blockIdx.x;
    if (b < NROWS + 1) {
        int o = threadIdx.x;
        if (b == NROWS) { Etab[(size_t)b * SC_OUT + o] = 0; return; }
        int j = b / CT, ct = b % CT, c = ct / N_AT, t = ct % N_AT;
        float s = Ec[((size_t)j * N_AC + c) * SC_OUT + o] +
                  Et[((size_t)j * N_AT + t) * SC_OUT + o];
        Etab[(size_t)b * SC_OUT + o] = f2bf(s);
        return;
    }
    int i = (b - (NROWS + 1)) * 256 + threadIdx.x;
    if (i >= R * P) return;
    int r = i / P, s = i % P;
    int st = starts[r];
    int cnt = ends[r] - st;
    if (cnt > P) cnt = P;
    uint4 q = make_uint4(ZROWB, 0u, 0u, 0u);
    if (s < cnt) {
        int ai = st + s;
        q.x = (uint32_t)((s * CT + ac[ai] * N_AT + at[ai]) * ROWB);
        q.y = __float_as_uint(rel[(size_t)3 * ai]);
        q.z = __float_as_uint(rel[(size_t)3 * ai + 1]);
        q.w = __float_as_uint(rel[(size_t)3 * ai + 2]);
    }
    plan[i] = q;
}

// ---- K4: one wave per residue ----------------------------------------------
__global__ __launch_bounds__(256) void k4_residue(
        const float* __restrict__ base, const int* __restrict__ rcode,
        const int* __restrict__ rseq, const int* __restrict__ starts,
        const int* __restrict__ ends, const uint4* __restrict__ plan,
        const unsigned char* __restrict__ tab, const float* __restrict__ Erc,
        const float* __restrict__ Erix, const float* __restrict__ Wvec,
        float* __restrict__ out_coords, float* __restrict__ out_feat, int R) {
    __shared__ float lds_w[P * VEC_OUT];   // 6 KB
    for (int t = threadIdx.x; t < P * VEC_OUT; t += 256) lds_w[t] = Wvec[t];
    __syncthreads();

    int wid = (blockIdx.x << 2) + (threadIdx.x >> 6);
    int lane = threadIdx.x & 63;
    int r = __builtin_amdgcn_readfirstlane(wid);   // provably wave-uniform
    if (r >= R) return;

    int cnt = ends[r] - starts[r];
    if (cnt > P) cnt = P;

    float4 ea = *reinterpret_cast<const float4*>(Erc + (size_t)rcode[r] * SC_OUT + lane * 4);
    float4 eb = *reinterpret_cast<const float4*>(Erix + (size_t)rseq[r] * SC_OUT + lane * 4);
    float a0 = ea.x + eb.x, a1 = ea.y + eb.y, a2 = ea.z + eb.z, a3 = ea.w + eb.w;
    float v0 = 0.f, v1 = 0.f, v2 = 0.f;
    const int lb = lane * 8;

    float w[16];
#pragma unroll
    for (int k = 0; k < 16; ++k) w[k] = lds_w[k * VEC_OUT + lane];

    const uint4* pp = plan + (size_t)r * P;        // uniform -> s_load
    uint4 q[16];
#pragma unroll
    for (int k = 0; k < 16; ++k) q[k] = pp[k];

    uint2 g[16];
#pragma unroll
    for (int k = 0; k < 16; ++k)
        g[k] = *reinterpret_cast<const uint2*>(tab + q[k].x + lb);

#pragma unroll
    for (int k = 0; k < 16; ++k) {
        a0 += __uint_as_float(g[k].x << 16);
        a1 += __uint_as_float(g[k].x & 0xFFFF0000u);
        a2 += __uint_as_float(g[k].y << 16);
        a3 += __uint_as_float(g[k].y & 0xFFFF0000u);
        v0 = fmaf(__uint_as_float(q[k].y), w[k], v0);
        v1 = fmaf(__uint_as_float(q[k].z), w[k], v1);
        v2 = fmaf(__uint_as_float(q[k].w), w[k], v2);
    }
    if (cnt > 16) {                                 // generic tail (unused when APR<=16)
#pragma unroll
        for (int k = 16; k < P; ++k) {
            uint4 qq = pp[k];
            uint2 gg = *reinterpret_cast<const uint2*>(tab + qq.x + lb);
            float ww = lds_w[k * VEC_OUT + lane];
            a0 += __uint_as_float(gg.x << 16);
            a1 += __uint_as_float(gg.x & 0xFFFF0000u);
            a2 += __uint_as_float(gg.y << 16);
            a3 += __uint_as_float(gg.y & 0xFFFF0000u);
            v0 = fmaf(__uint_as_float(qq.y), ww, v0);
            v1 = fmaf(__uint_as_float(qq.z), ww, v1);
            v2 = fmaf(__uint_as_float(qq.w), ww, v2);
        }
    }

    const float vs = 0.20412414523193150818f;  // 1/sqrt(24)
    float* frow = out_feat + (size_t)r * FEAT;
    frow[lane * 3 + 0] = v0 * vs;
    frow[lane * 3 + 1] = v1 * vs;
    frow[lane * 3 + 2] = v2 * vs;
    *reinterpret_cast<float4*>(frow + 3 * VEC_OUT + lane * 4) =
        make_float4(a0, a1, a2, a3);
    if (lane < 3) out_coords[(size_t)r * 3 + lane] = base[(size_t)r * 3 + lane];
}

extern "C" void kernel_launch(void* const* d_in, const int* in_sizes, int n_in,
                              void* d_out, int out_size, void* d_ws, size_t ws_size,
                              hipStream_t stream) {
    const float* base  = (const float*)d_in[0];
    const float* rel   = (const float*)d_in[1];
    const int*   rcode = (const int*)d_in[2];
    const int*   rseq  = (const int*)d_in[3];
    const int*   acode = (const int*)d_in[4];
    const int*   atype = (const int*)d_in[5];
    const int*   ri    = (const int*)d_in[6];
    const float* Wac   = (const float*)d_in[7];
    const float* Wat   = (const float*)d_in[8];
    const float* Wrc   = (const float*)d_in[9];
    const float* Wri   = (const float*)d_in[10];
    const float* Wv    = (const float*)d_in[11];
    const float* Wsc   = (const float*)d_in[12];

    const int R = in_sizes[0] / 3;
    const int N = in_sizes[6];

    float* out_coords = (float*)d_out;
    float* out_feat   = out_coords + (size_t)R * 3;

    char* ws = (char*)d_ws;
    size_t ofs = 0;
    auto alloc = [&](size_t bytes) {
        void* p = ws + ofs;
        ofs = (ofs + bytes + 255) & ~255ULL;
        return p;
    };
    int*            starts = (int*)alloc((size_t)R * 4);
    int*            ends   = (int*)alloc((size_t)R * 4);
    float*          Ec_f   = (float*)alloc((size_t)P * N_AC * SC_OUT * 4);
    float*          Et_f   = (float*)alloc((size_t)P * N_AT * SC_OUT * 4);
    float*          Erc_f  = (float*)alloc((size_t)N_RC * SC_OUT * 4);
    float*          Erix_f = (float*)alloc((size_t)MAXSEQ * SC_OUT * 4);
    unsigned short* Etab   = (unsigned short*)alloc((size_t)(NROWS + 1) * SC_OUT * 2);
    uint4*          plan   = (uint4*)alloc((size_t)R * P * 16);
    (void)ws_size; (void)n_in; (void)out_size;

    const int initB  = (R + 255) / 256;
    const int k1B    = initB + P * N_AC + P * N_AT + N_RC + MAXSEQ;
    const int planB  = (R * P + 255) / 256;
    const int k3B    = (NROWS + 1) + planB;

    k1_init_build<<<k1B, 256, 0, stream>>>(Wac, Wat, Wrc, Wri, Wsc,
                                           Ec_f, Et_f, Erc_f, Erix_f, starts, ends, R);
    k2_find_bounds<<<(N + 255) / 256, 256, 0, stream>>>(ri, starts, ends, N);
    k3_fuse_plan<<<k3B, 256, 0, stream>>>(Ec_f, Et_f, Etab, acode, atype,
                                          starts, ends, rel, plan, R);
    k4_residue<<<(R + 3) / 4, 256, 0, stream>>>(
        base, rcode, rseq, starts, ends, plan, (const unsigned char*)Etab,
        Erc_f, Erix_f, Wv, out_coords, out_feat, R);
}

// Round 4
// 63.800 us; speedup vs baseline: 1.5829x; 1.0453x over previous
//
#include <hip/hip_runtime.h>
#include <stdint.h>

static constexpr int P       = 24;
static constexpr int EMB_D   = 32;
static constexpr int N_AC    = 38;
static constexpr int N_AT    = 6;
static constexpr int N_RC    = 21;
static constexpr int MAXSEQ  = 1024;
static constexpr int VEC_OUT = 64;
static constexpr int SC_OUT  = 256;
static constexpr int FEAT    = 3 * VEC_OUT + SC_OUT;   // 448
static constexpr int CT      = N_AC * N_AT;            // 228
static constexpr int NROWS   = P * CT;                 // 5472
static constexpr int ROWB    = SC_OUT * 2;             // 512 B bf16 row
static constexpr uint32_t ZROWB = (uint32_t)NROWS * ROWB;  // zero row offset

__device__ __forceinline__ unsigned short f2bf(float f) {
    uint32_t x = __float_as_uint(f);
    uint32_t r = (x + 0x7FFFu + ((x >> 16) & 1u)) >> 16;  // RNE
    return (unsigned short)r;
}

// ---- K1: init bounds + build all four f32 partial tables -------------------
__global__ __launch_bounds__(256) void k1_init_build(
        const float* __restrict__ Wac, const float* __restrict__ Wat,
        const float* __restrict__ Wrc, const float* __restrict__ Wri,
        const float* __restrict__ Wsc,
        float* __restrict__ Ec, float* __restrict__ Et,
        float* __restrict__ Erc, float* __restrict__ Erix,
        int* __restrict__ starts, int* __restrict__ ends, int R) {
    int b = blockIdx.x;
    const int initB = (R + 255) / 256;
    if (b < initB) {
        int i = b * 256 + threadIdx.x;
        if (i < R) { starts[i] = 0; ends[i] = 0; }
        return;
    }
    b -= initB;
    const float* Wemb; float* E; int n_emb, sc_base, idx;
    if (b < P * N_AC) {
        Wemb = Wac; E = Ec; n_emb = N_AC; sc_base = 0; idx = b;
    } else if (b < P * N_AC + P * N_AT) {
        Wemb = Wat; E = Et; n_emb = N_AT; sc_base = P * EMB_D; idx = b - P * N_AC;
    } else if (b < P * N_AC + P * N_AT + N_RC) {
        Wemb = Wrc; E = Erc; n_emb = N_RC; sc_base = 2 * P * EMB_D;
        idx = b - (P * N_AC + P * N_AT);
    } else {
        Wemb = Wri; E = Erix; n_emb = MAXSEQ; sc_base = 2 * P * EMB_D + EMB_D;
        idx = b - (P * N_AC + P * N_AT + N_RC);
    }
    int p = idx / n_emb, e = idx % n_emb;
    int o = threadIdx.x;
    const float* wrow = Wemb + (size_t)e * EMB_D;
    const float* scol = Wsc + (size_t)(sc_base + p * EMB_D) * SC_OUT + o;
    float s = 0.f;
#pragma unroll
    for (int d = 0; d < EMB_D; ++d) s += wrow[d] * scol[(size_t)d * SC_OUT];
    E[(size_t)idx * SC_OUT + o] = s * 0.025f;  // 1/sqrt(1600)
}

// ---- K2: residue run boundaries (ri sorted) --------------------------------
__global__ void k2_find_bounds(const int* __restrict__ ri, int* __restrict__ starts,
                               int* __restrict__ ends, int N) {
    int i = blockIdx.x * blockDim.x + threadIdx.x;
    if (i >= N) return;
    int r = ri[i];
    if (i == 0 || ri[i - 1] != r) starts[r] = i;
    if (i == N - 1 || ri[i + 1] != r) ends[r] = i + 1;
}

// ---- K3: fuse code+type table to bf16  +  pack per-residue header ----------
__global__ __launch_bounds__(256) void k3_fuse_hdr(
        const float* __restrict__ Ec, const float* __restrict__ Et,
        unsigned short* __restrict__ Etab,
        const int* __restrict__ starts, const int* __restrict__ ends,
        const int* __restrict__ rcode, const int* __restrict__ rseq,
        int4* __restrict__ hdr, int R) {
    int b = blockIdx.x;
    if (b < NROWS + 1) {
        int o = threadIdx.x;
        if (b == NROWS) { Etab[(size_t)b * SC_OUT + o] = 0; return; }
        int j = b / CT, ct = b % CT, c = ct / N_AT, t = ct % N_AT;
        float s = Ec[((size_t)j * N_AC + c) * SC_OUT + o] +
                  Et[((size_t)j * N_AT + t) * SC_OUT + o];
        Etab[(size_t)b * SC_OUT + o] = f2bf(s);
        return;
    }
    int i = (b - (NROWS + 1)) * 256 + threadIdx.x;
    if (i >= R) return;
    int st = starts[i];
    int c = ends[i] - st;
    if (c > P) c = P;
    hdr[i] = make_int4(st, c, rcode[i], rseq[i]);
}

// ---- K4: one wave per residue ----------------------------------------------
__global__ __launch_bounds__(256) void k4_residue(
        const float* __restrict__ base, const int4* __restrict__ hdr,
        const int* __restrict__ acode, const int* __restrict__ atype,
        const float* __restrict__ rel, const unsigned char* __restrict__ tab,
        const float* __restrict__ Erc, const float* __restrict__ Erix,
        const float* __restrict__ Wvec,
        float* __restrict__ out_coords, float* __restrict__ out_feat,
        int R, int N) {
    __shared__ float lds_w[P * VEC_OUT];   // 6 KB
    for (int t = threadIdx.x; t < P * VEC_OUT; t += 256) lds_w[t] = Wvec[t];
    __syncthreads();

    int wid = (blockIdx.x << 2) + (threadIdx.x >> 6);
    int lane = threadIdx.x & 63;
    int r = __builtin_amdgcn_readfirstlane(wid);
    if (r >= R) return;

    int4 h = hdr[r];                       // uniform -> one s_load_dwordx4
    const int off = h.x, cnt = h.y;

    // lane-parallel raw inputs (coalesced VMEM)
    int ia = off + lane; if (ia > N - 1) ia = N - 1;
    int code = acode[ia];
    int type = atype[ia];
    uint32_t rowoff = ZROWB;
    if (lane < cnt) rowoff = (uint32_t)((lane * CT + code * N_AT + type) * ROWB);
    int ir = 3 * off + lane; if (ir > 3 * N - 1) ir = 3 * N - 1;
    float relv = rel[ir];
    if (lane >= 3 * cnt) relv = 0.f;

    float4 ea = *reinterpret_cast<const float4*>(Erc + (size_t)h.z * SC_OUT + lane * 4);
    float4 eb = *reinterpret_cast<const float4*>(Erix + (size_t)h.w * SC_OUT + lane * 4);
    float a0 = ea.x + eb.x, a1 = ea.y + eb.y, a2 = ea.z + eb.z, a3 = ea.w + eb.w;
    float v0 = 0.f, v1 = 0.f, v2 = 0.f;
    const int lb = lane * 8;

    // broadcast per-slot row offsets to SGPRs, then wave-uniform coalesced gathers
    uint32_t ro[16];
#pragma unroll
    for (int k = 0; k < 16; ++k)
        ro[k] = (uint32_t)__builtin_amdgcn_readlane((int)rowoff, k);
    uint2 g[16];
#pragma unroll
    for (int k = 0; k < 16; ++k)
        g[k] = *reinterpret_cast<const uint2*>(tab + ro[k] + lb);

    float rx[16], ry[16], rz[16];
#pragma unroll
    for (int k = 0; k < 16; ++k) {
        rx[k] = __int_as_float(__builtin_amdgcn_readlane(__float_as_int(relv), 3 * k));
        ry[k] = __int_as_float(__builtin_amdgcn_readlane(__float_as_int(relv), 3 * k + 1));
        rz[k] = __int_as_float(__builtin_amdgcn_readlane(__float_as_int(relv), 3 * k + 2));
    }

#pragma unroll
    for (int k = 0; k < 16; ++k) {
        float w = lds_w[k * VEC_OUT + lane];
        a0 += __uint_as_float(g[k].x << 16);
        a1 += __uint_as_float(g[k].x & 0xFFFF0000u);
        a2 += __uint_as_float(g[k].y << 16);
        a3 += __uint_as_float(g[k].y & 0xFFFF0000u);
        v0 = fmaf(rx[k], w, v0);
        v1 = fmaf(ry[k], w, v1);
        v2 = fmaf(rz[k], w, v2);
    }

    if (cnt > 16) {                        // cold general tail (APR<=16 skips)
        int ir2 = 3 * off + 64 + lane;
        if (ir2 > 3 * N - 1) ir2 = 3 * N - 1;
        float relv2 = rel[ir2];
        if (64 + lane >= 3 * cnt) relv2 = 0.f;
#pragma unroll
        for (int k = 16; k < P; ++k) {
            uint32_t rr = (uint32_t)__builtin_amdgcn_readlane((int)rowoff, k);
            uint2 gg = *reinterpret_cast<const uint2*>(tab + rr + lb);
            float w = lds_w[k * VEC_OUT + lane];
            float sx = __int_as_float(3 * k < 64
                ? __builtin_amdgcn_readlane(__float_as_int(relv), 3 * k)
                : __builtin_amdgcn_readlane(__float_as_int(relv2), 3 * k - 64));
            float sy = __int_as_float(3 * k + 1 < 64
                ? __builtin_amdgcn_readlane(__float_as_int(relv), 3 * k + 1)
                : __builtin_amdgcn_readlane(__float_as_int(relv2), 3 * k + 1 - 64));
            float sz = __int_as_float(3 * k + 2 < 64
                ? __builtin_amdgcn_readlane(__float_as_int(relv), 3 * k + 2)
                : __builtin_amdgcn_readlane(__float_as_int(relv2), 3 * k + 2 - 64));
            a0 += __uint_as_float(gg.x << 16);
            a1 += __uint_as_float(gg.x & 0xFFFF0000u);
            a2 += __uint_as_float(gg.y << 16);
            a3 += __uint_as_float(gg.y & 0xFFFF0000u);
            v0 = fmaf(sx, w, v0);
            v1 = fmaf(sy, w, v1);
            v2 = fmaf(sz, w, v2);
        }
    }

    const float vs = 0.20412414523193150818f;  // 1/sqrt(24)
    float* frow = out_feat + (size_t)r * FEAT;
    frow[lane * 3 + 0] = v0 * vs;
    frow[lane * 3 + 1] = v1 * vs;
    frow[lane * 3 + 2] = v2 * vs;
    *reinterpret_cast<float4*>(frow + 3 * VEC_OUT + lane * 4) =
        make_float4(a0, a1, a2, a3);
    if (lane < 3) out_coords[(size_t)r * 3 + lane] = base[(size_t)r * 3 + lane];
}

extern "C" void kernel_launch(void* const* d_in, const int* in_sizes, int n_in,
                              void* d_out, int out_size, void* d_ws, size_t ws_size,
                              hipStream_t stream) {
    const float* base  = (const float*)d_in[0];
    const float* rel   = (const float*)d_in[1];
    const int*   rcode = (const int*)d_in[2];
    const int*   rseq  = (const int*)d_in[3];
    const int*   acode = (const int*)d_in[4];
    const int*   atype = (const int*)d_in[5];
    const int*   ri    = (const int*)d_in[6];
    const float* Wac   = (const float*)d_in[7];
    const float* Wat   = (const float*)d_in[8];
    const float* Wrc   = (const float*)d_in[9];
    const float* Wri   = (const float*)d_in[10];
    const float* Wv    = (const float*)d_in[11];
    const float* Wsc   = (const float*)d_in[12];

    const int R = in_sizes[0] / 3;
    const int N = in_sizes[6];

    float* out_coords = (float*)d_out;
    float* out_feat   = out_coords + (size_t)R * 3;

    char* ws = (char*)d_ws;
    size_t ofs = 0;
    auto alloc = [&](size_t bytes) {
        void* p = ws + ofs;
        ofs = (ofs + bytes + 255) & ~255ULL;
        return p;
    };
    int*            starts = (int*)alloc((size_t)R * 4);
    int*            ends   = (int*)alloc((size_t)R * 4);
    float*          Ec_f   = (float*)alloc((size_t)P * N_AC * SC_OUT * 4);
    float*          Et_f   = (float*)alloc((size_t)P * N_AT * SC_OUT * 4);
    float*          Erc_f  = (float*)alloc((size_t)N_RC * SC_OUT * 4);
    float*          Erix_f = (float*)alloc((size_t)MAXSEQ * SC_OUT * 4);
    unsigned short* Etab   = (unsigned short*)alloc((size_t)(NROWS + 1) * SC_OUT * 2);
    int4*           hdr    = (int4*)alloc((size_t)R * 16);
    (void)ws_size; (void)n_in; (void)out_size;

    const int initB = (R + 255) / 256;
    const int k1B   = initB + P * N_AC + P * N_AT + N_RC + MAXSEQ;
    const int hdrB  = (R + 255) / 256;
    const int k3B   = (NROWS + 1) + hdrB;

    k1_init_build<<<k1B, 256, 0, stream>>>(Wac, Wat, Wrc, Wri, Wsc,
                                           Ec_f, Et_f, Erc_f, Erix_f, starts, ends, R);
    k2_find_bounds<<<(N + 255) / 256, 256, 0, stream>>>(ri, starts, ends, N);
    k3_fuse_hdr<<<k3B, 256, 0, stream>>>(Ec_f, Et_f, Etab, starts, ends,
                                         rcode, rseq, hdr, R);
    k4_residue<<<(R + 3) / 4, 256, 0, stream>>>(
        base, hdr, acode, atype, rel, (const unsigned char*)Etab,
        Erc_f, Erix_f, Wv, out_coords, out_feat, R, N);
}